// Round 4
// baseline (16205.464 us; speedup 1.0000x reference)
//
#include <hip/hip_runtime.h>
#include <cstdint>

#define NPTS 32768
#define DIM  256
#define NK   128
#define NITER 100
#define NBLK 256

typedef __attribute__((ext_vector_type(8))) short s8v;   // 8 bf16 in 4 VGPRs
typedef __attribute__((ext_vector_type(4))) float f4v;   // MFMA accumulator

__device__ __forceinline__ unsigned short f2bf(float f) {
  unsigned u = __float_as_uint(f);
  u += 0x7fffu + ((u >> 16) & 1u);      // RTNE
  return (unsigned short)(u >> 16);
}
__device__ __forceinline__ float bf2f(unsigned short b) {
  return __uint_as_float(((unsigned)b) << 16);
}

// ---- device-scope grid barrier (sense-reversal), state in d_ws, zeroed per launch ----
// bar[0] = arrive counter, bar[1] = generation. Co-residency guaranteed:
// 132KB LDS -> 1 block/CU, grid = 256 = #CUs, __launch_bounds__(256,1).
__device__ __forceinline__ void gbar(unsigned* bar) {
  __syncthreads();
  if (threadIdx.x == 0) {
    __threadfence();                                    // release my block's writes (L2 wb)
    unsigned g = __hip_atomic_load(&bar[1], __ATOMIC_RELAXED, __HIP_MEMORY_SCOPE_AGENT);
    unsigned a = __hip_atomic_fetch_add(&bar[0], 1u, __ATOMIC_ACQ_REL, __HIP_MEMORY_SCOPE_AGENT);
    if (a == (unsigned)NBLK - 1u) {
      __hip_atomic_store(&bar[0], 0u, __ATOMIC_RELAXED, __HIP_MEMORY_SCOPE_AGENT);
      __hip_atomic_store(&bar[1], g + 1u, __ATOMIC_RELEASE, __HIP_MEMORY_SCOPE_AGENT);
    } else {
      while (__hip_atomic_load(&bar[1], __ATOMIC_RELAXED, __HIP_MEMORY_SCOPE_AGENT) == g) {
        __builtin_amdgcn_s_sleep(2);
      }
    }
    __threadfence();                                    // acquire others' writes (inv)
  }
  __syncthreads();
}

// Shared-memory overlay: phase A (GEMM) / phase B (update) / phase C (small reduces)
union SMu {
  struct {
    s8v bufs[4][2048];        // XH, XL, CH, CL half-D tiles, 32 KB each = 128 KB
    float cns[NK];
    float redd[NK * 2];
    int   redk[NK * 2];
    float gmaxs[NK];
    float labvs[NK];
    int   labis[NK];
  } a;
  struct {
    float ls[NK * 32];        // 16 KB
    float lc[NK];
    int   idsl[1024];
  } b;
  struct {
    float red[256];
  } c;
};

// GEMM core: stages hi/lo x and c tiles (XOR-swizzled), 3-pass bf16 MFMA.
// acc[i][j][r] = x_p . c_k  to ~2^-16 relative accuracy.
__device__ __forceinline__ void gemm_core(
    SMu& sm, int b, int t,
    const unsigned short* __restrict__ xh, const unsigned short* __restrict__ xl,
    const unsigned short* __restrict__ chi, const unsigned short* __restrict__ clo,
    const float* __restrict__ cn, f4v (&acc)[4][4]) {
  const int lane = t & 63;
  const int w    = t >> 6;
  const int wr   = w >> 1, wc = w & 1;    // 2x2 wave grid, 64x64 tile each
  const int g    = lane >> 4, lr = lane & 15;
  const int pbase = b * 128;

  if (t < NK) sm.a.cns[t] = cn[t];

  const f4v zero = {0.f, 0.f, 0.f, 0.f};
#pragma unroll
  for (int i = 0; i < 4; ++i)
#pragma unroll
    for (int j = 0; j < 4; ++j) acc[i][j] = zero;

  const int swz = (lr & 7) << 4;
  int a_off[4], b_off[4];
#pragma unroll
  for (int i = 0; i < 4; ++i) a_off[i] = (wr * 64 + i * 16 + lr) * 256 + g * 16;
#pragma unroll
  for (int j = 0; j < 4; ++j) b_off[j] = (wc * 64 + j * 16 + lr) * 256 + g * 16;

  const unsigned short* srcs[4];
  srcs[0] = xh + pbase * DIM;
  srcs[1] = xl + pbase * DIM;
  srcs[2] = chi;
  srcs[3] = clo;

  for (int h = 0; h < 2; ++h) {           // two D-halves of 128
    __syncthreads();
#pragma unroll
    for (int bb = 0; bb < 4; ++bb) {
      const char* sp = (const char*)srcs[bb];
      char* dp = (char*)sm.a.bufs[bb];
#pragma unroll
      for (int i = 0; i < 8; ++i) {
        int gg = i * 256 + t;             // granule within 32KB buffer
        int row = gg >> 4, whb = (gg & 15) * 16;
        s8v v = *(const s8v*)(sp + row * 512 + h * 256 + whb);
        *(s8v*)(dp + ((gg * 16) ^ ((row & 7) << 4))) = v;
      }
    }
    __syncthreads();
#pragma unroll
    for (int kk = 0; kk < 4; ++kk) {      // K=128 per half, 4 steps of 32
      s8v ah[4], al[4], bh[4], bl[4];
#pragma unroll
      for (int i = 0; i < 4; ++i) {
        int o = (a_off[i] + kk * 64) ^ swz;
        ah[i] = *(const s8v*)((const char*)sm.a.bufs[0] + o);
        al[i] = *(const s8v*)((const char*)sm.a.bufs[1] + o);
      }
#pragma unroll
      for (int j = 0; j < 4; ++j) {
        int o = (b_off[j] + kk * 64) ^ swz;
        bh[j] = *(const s8v*)((const char*)sm.a.bufs[2] + o);
        bl[j] = *(const s8v*)((const char*)sm.a.bufs[3] + o);
      }
#pragma unroll
      for (int i = 0; i < 4; ++i)
#pragma unroll
        for (int j = 0; j < 4; ++j) {
          acc[i][j] = __builtin_amdgcn_mfma_f32_16x16x32_bf16(ah[i], bh[j], acc[i][j], 0, 0, 0);
          acc[i][j] = __builtin_amdgcn_mfma_f32_16x16x32_bf16(ah[i], bl[j], acc[i][j], 0, 0, 0);
          acc[i][j] = __builtin_amdgcn_mfma_f32_16x16x32_bf16(al[i], bh[j], acc[i][j], 0, 0, 0);
        }
    }
  }
}

__global__ __launch_bounds__(256, 1) void kmeans_fused(
    const float* __restrict__ x, const int* __restrict__ init_idx,
    unsigned short* __restrict__ xh, unsigned short* __restrict__ xl,
    unsigned short* __restrict__ chi, unsigned short* __restrict__ clo,
    float* __restrict__ cn, int* __restrict__ ids,
    float* __restrict__ psum, float* __restrict__ pcnt,
    float* __restrict__ outp, unsigned* __restrict__ bar,
    float* __restrict__ out) {
  __shared__ SMu sm;

  const int b = blockIdx.x;
  const int t = threadIdx.x;
  const int lane = t & 63;
  const int w  = t >> 6;
  const int wr = w >> 1, wc = w & 1;
  const int g  = lane >> 4, lr = lane & 15;
  const int pbase = b * 128;

  // ---------------- prep: x -> bf16 hi/lo images (once) ----------------
  for (int i = 0; i < 16; ++i) {
    int gg = b * 4096 + i * 256 + t;      // 16B granule = 8 elems
    const float4* src = (const float4*)x + gg * 2;
    float4 fa = src[0], fb = src[1];
    float vv[8] = {fa.x, fa.y, fa.z, fa.w, fb.x, fb.y, fb.z, fb.w};
    s8v vh, vl;
#pragma unroll
    for (int j = 0; j < 8; ++j) {
      unsigned short hh = f2bf(vv[j]);
      vh[j] = (short)hh;
      vl[j] = (short)f2bf(vv[j] - bf2f(hh));
    }
    ((s8v*)xh)[gg] = vh;
    ((s8v*)xl)[gg] = vl;
  }

  // ---------------- init: c0 = x[init_idx] -> hi/lo + cn ----------------
  if (b < NK) {
    float v = x[init_idx[b] * DIM + t];
    unsigned short hh = f2bf(v);
    unsigned short ll = f2bf(v - bf2f(hh));
    chi[b * DIM + t] = hh;
    clo[b * DIM + t] = ll;
    float eff = bf2f(hh) + bf2f(ll);
    sm.c.red[t] = eff * eff;
    __syncthreads();
    for (int s = 128; s > 0; s >>= 1) { if (t < s) sm.c.red[t] += sm.c.red[t + s]; __syncthreads(); }
    if (t == 0) cn[b] = sm.c.red[0];
  }
  gbar(bar);

  // ---------------- main loop: 100 x (assign -> update -> reduce) ----------------
  for (int it = 0; it < NITER; ++it) {
    // ---- phase A: assign ----
    {
      f4v acc[4][4];
      gemm_core(sm, b, t, xh, xl, chi, clo, cn, acc);
      // D layout: col = lane&15, row(16x16) = (lane>>4)*4 + reg
#pragma unroll
      for (int i = 0; i < 4; ++i) {
#pragma unroll
        for (int r = 0; r < 4; ++r) {
          int prow = wr * 64 + i * 16 + g * 4 + r;
          float bd = 1e30f; int bk = 0;
#pragma unroll
          for (int j = 0; j < 4; ++j) {
            int col = wc * 64 + j * 16 + lr;
            float s = sm.a.cns[col] - 2.f * acc[i][j][r];
            if (s < bd || (s == bd && col < bk)) { bd = s; bk = col; }
          }
#pragma unroll
          for (int msk = 1; msk < 16; msk <<= 1) {
            float od = __shfl_xor(bd, msk, 64);
            int   ok = __shfl_xor(bk, msk, 64);
            if (od < bd || (od == bd && ok < bk)) { bd = od; bk = ok; }
          }
          if (lr == 0) { sm.a.redd[prow * 2 + wc] = bd; sm.a.redk[prow * 2 + wc] = bk; }
        }
      }
      __syncthreads();
      if (t < NK) {
        float d0 = sm.a.redd[t * 2], d1 = sm.a.redd[t * 2 + 1];
        int k0 = sm.a.redk[t * 2], k1 = sm.a.redk[t * 2 + 1];
        ids[pbase + t] = (d1 < d0 || (d1 == d0 && k1 < k0)) ? k1 : k0;
      }
    }
    gbar(bar);

    // ---- phase B: update partial segment sums (32 pc x 8 dc) ----
    {
      const int pc = b & 31, dc = b >> 5;
      for (int r = t; r < NK * 32; r += 256) sm.b.ls[r] = 0.f;
      if (t < NK) sm.b.lc[t] = 0.f;
      for (int r = t; r < 1024; r += 256) sm.b.idsl[r] = ids[pc * 1024 + r];
      __syncthreads();
      const int sub = t >> 5, dl = t & 31;
      const int dcol = dc * 32 + dl;
      for (int s = 0; s < 128; ++s) {
        int pl = s * 8 + sub;
        int id = sm.b.idsl[pl];
        float v = x[(pc * 1024 + pl) * DIM + dcol];
        atomicAdd(&sm.b.ls[id * 32 + dl], v);
        if (dc == 0 && dl == 0) atomicAdd(&sm.b.lc[id], 1.f);
      }
      __syncthreads();
      for (int r = 0; r < 16; ++r) {
        int idx = r * 256 + t;
        int k = idx >> 5, d2 = idx & 31;
        psum[(pc * NK + k) * DIM + dc * 32 + d2] = sm.b.ls[k * 32 + d2];
      }
      if (dc == 0 && t < NK) pcnt[pc * NK + t] = sm.b.lc[t];
    }
    gbar(bar);

    // ---- phase C: reduce partials -> means -> hi/lo images + cn ----
    if (b < NK) {
      float s = 0.f;
      for (int pc = 0; pc < 32; ++pc) s += psum[(pc * NK + b) * DIM + t];
      float cntv = 0.f;
      for (int pc = 0; pc < 32; ++pc) cntv += pcnt[pc * NK + b];
      float mean = s / cntv;               // NaN for empty cluster, like reference
      unsigned short hh = f2bf(mean);
      unsigned short ll = f2bf(mean - bf2f(hh));
      chi[b * DIM + t] = hh;
      clo[b * DIM + t] = ll;
      float eff = bf2f(hh) + bf2f(ll);
      sm.c.red[t] = eff * eff;
      __syncthreads();
      for (int st = 128; st > 0; st >>= 1) { if (t < st) sm.c.red[t] += sm.c.red[t + st]; __syncthreads(); }
      if (t == 0) cn[b] = sm.c.red[0];
    }
    gbar(bar);
  }

  // ---------------- final: loss (log-softmax + CE), deterministic reduce ----------------
  {
    f4v acc[4][4];
    gemm_core(sm, b, t, xh, xl, chi, clo, cn, acc);
#pragma unroll
    for (int i = 0; i < 4; ++i) {
#pragma unroll
      for (int r = 0; r < 4; ++r) {
        int prow = wr * 64 + i * 16 + g * 4 + r;
        float m = -1e30f;
#pragma unroll
        for (int j = 0; j < 4; ++j) m = fmaxf(m, acc[i][j][r]);
#pragma unroll
        for (int msk = 1; msk < 16; msk <<= 1) m = fmaxf(m, __shfl_xor(m, msk, 64));
        if (lr == 0) sm.a.redd[prow * 2 + wc] = m;
      }
    }
    __syncthreads();
    if (t < NK) {
      sm.a.gmaxs[t] = fmaxf(sm.a.redd[t * 2], sm.a.redd[t * 2 + 1]);
      sm.a.labis[t] = ids[pbase + t];
    }
    __syncthreads();
#pragma unroll
    for (int i = 0; i < 4; ++i) {
#pragma unroll
      for (int r = 0; r < 4; ++r) {
        int prow = wr * 64 + i * 16 + g * 4 + r;
        float m = sm.a.gmaxs[prow];
        int lab = sm.a.labis[prow];
        float s = 0.f;
#pragma unroll
        for (int j = 0; j < 4; ++j) {
          int col = wc * 64 + j * 16 + lr;
          float v = acc[i][j][r];
          s += expf(v - m);
          if (col == lab) sm.a.labvs[prow] = v;
        }
#pragma unroll
        for (int msk = 1; msk < 16; msk <<= 1) s += __shfl_xor(s, msk, 64);
        if (lr == 0) sm.a.redd[prow * 2 + wc] = s;
      }
    }
    __syncthreads();
    if (t < NK) {
      float se  = sm.a.redd[t * 2] + sm.a.redd[t * 2 + 1];
      float lse = sm.a.gmaxs[t] + logf(se);
      sm.a.gmaxs[t] = lse - sm.a.labvs[t];
    }
    __syncthreads();
    if (t == 0) {
      float tot = 0.f;
      for (int q = 0; q < NK; ++q) tot += sm.a.gmaxs[q];
      outp[b] = tot;
    }
  }
  gbar(bar);
  if (b == 0) {
    sm.c.red[t] = outp[t];
    __syncthreads();
    for (int s = 128; s > 0; s >>= 1) { if (t < s) sm.c.red[t] += sm.c.red[t + s]; __syncthreads(); }
    if (t == 0) out[0] = sm.c.red[0] * (1.0f / (float)NPTS);
  }
}

extern "C" void kernel_launch(void* const* d_in, const int* in_sizes, int n_in,
                              void* d_out, int out_size, void* d_ws, size_t ws_size,
                              hipStream_t stream) {
  const float* x        = (const float*)d_in[0];
  const int*   init_idx = (const int*)d_in[1];
  float* out = (float*)d_out;
  char* ws = (char*)d_ws;

  // ws layout (bytes):
  unsigned short* xh  = (unsigned short*)(ws);                   // 16777216
  unsigned short* xl  = (unsigned short*)(ws + 16777216);        // 16777216
  unsigned short* chi = (unsigned short*)(ws + 33554432);        // 65536
  unsigned short* clo = (unsigned short*)(ws + 33619968);        // 65536
  float* cn   = (float*)(ws + 33685504);                         // 512
  int*   ids  = (int*)(ws + 33686016);                           // 131072
  float* psum = (float*)(ws + 33817088);                         // 4194304
  float* pcnt = (float*)(ws + 38011392);                         // 16384
  float* outp = (float*)(ws + 38027776);                         // 1024
  unsigned* bar = (unsigned*)(ws + 38028800);                    // 256

  // reset grid-barrier state every launch (graph replays include this node)
  hipMemsetAsync(bar, 0, 256, stream);
  kmeans_fused<<<dim3(NBLK), dim3(256), 0, stream>>>(
      x, init_idx, xh, xl, chi, clo, cn, ids, psum, pcnt, outp, bar, out);
}